// Round 8
// baseline (499.645 us; speedup 1.0000x reference)
//
#include <hip/hip_runtime.h>
#include <hip/hip_bf16.h>
#include <stdint.h>

#define NTOK 4096
#define DM 1024
#define FF 2048
#define F2 4096
#define NEXP 8
#define PAIR_CAP 10240   // 8192 pairs + 8*256 padding headroom

typedef __bf16 bf16x8 __attribute__((ext_vector_type(8)));
typedef float f32x4 __attribute__((ext_vector_type(4)));

__device__ __forceinline__ unsigned short bf16_rne(float f) {
    union { float f; unsigned int u; } v; v.f = f;
    unsigned int u = v.u;
    return (unsigned short)((u + 0x7FFFu + ((u >> 16) & 1u)) >> 16);
}

__device__ __forceinline__ f32x4 MFMA16(bf16x8 a, bf16x8 b, f32x4 c) {
    return __builtin_amdgcn_mfma_f32_16x16x32_bf16(a, b, c, 0, 0, 0);
}

__device__ __forceinline__ void gload16(const void* g, void* l) {
    __builtin_amdgcn_global_load_lds(
        (const __attribute__((address_space(1))) uint32_t*)g,
        (__attribute__((address_space(3))) uint32_t*)l, 16, 0, 0);
}

#define WAIT_LGKM0() do { asm volatile("s_waitcnt lgkmcnt(0)" ::: "memory"); __builtin_amdgcn_sched_barrier(0); } while (0)
#define WAIT_VM(n)   do { asm volatile("s_waitcnt vmcnt(" #n ")" ::: "memory"); __builtin_amdgcn_sched_barrier(0); } while (0)
#define BARRIER()    __builtin_amdgcn_s_barrier()

// ---------------- gating: scores (fp32), top-2 softmax, x -> bf16 ----------------
__global__ __launch_bounds__(64) void k_gate(const float* __restrict__ x,
                                             const float* __restrict__ Wg,
                                             unsigned short* __restrict__ xbf,
                                             int* __restrict__ te, float* __restrict__ tw,
                                             int* __restrict__ cnt) {
    int t = blockIdx.x;
    int l = threadIdx.x;
    const float* xr = x + (size_t)t * DM + l * 16;
    float xv[16];
#pragma unroll
    for (int i = 0; i < 4; ++i) {
        float4 v = ((const float4*)xr)[i];
        xv[4*i+0] = v.x; xv[4*i+1] = v.y; xv[4*i+2] = v.z; xv[4*i+3] = v.w;
    }
    unsigned int pk[8];
#pragma unroll
    for (int i = 0; i < 8; ++i)
        pk[i] = (unsigned int)bf16_rne(xv[2*i]) | ((unsigned int)bf16_rne(xv[2*i+1]) << 16);
    uint4* dst = (uint4*)(xbf + (size_t)t * DM + l * 16);
    dst[0] = make_uint4(pk[0], pk[1], pk[2], pk[3]);
    dst[1] = make_uint4(pk[4], pk[5], pk[6], pk[7]);

    float s[NEXP];
#pragma unroll
    for (int e = 0; e < NEXP; ++e) {
        const float* wr = Wg + e * DM + l * 16;
        float acc = 0.f;
#pragma unroll
        for (int i = 0; i < 4; ++i) {
            float4 v = ((const float4*)wr)[i];
            acc += v.x * xv[4*i] + v.y * xv[4*i+1] + v.z * xv[4*i+2] + v.w * xv[4*i+3];
        }
        s[e] = acc;
    }
#pragma unroll
    for (int off = 32; off > 0; off >>= 1) {
#pragma unroll
        for (int e = 0; e < NEXP; ++e) s[e] += __shfl_xor(s[e], off, 64);
    }
    if (l == 0) {
        int e0 = 0; float v0 = s[0];
        for (int e = 1; e < NEXP; ++e) if (s[e] > v0) { v0 = s[e]; e0 = e; }
        int e1 = -1; float v1 = -1e30f;
        for (int e = 0; e < NEXP; ++e) if (e != e0 && s[e] > v1) { v1 = s[e]; e1 = e; }
        float w0 = 1.f / (1.f + __expf(v1 - v0));
        float w1 = 1.f - w0;
        te[2*t] = e0; te[2*t+1] = e1;
        tw[2*t] = w0; tw[2*t+1] = w1;
        atomicAdd(&cnt[e0], 1); atomicAdd(&cnt[e1], 1);
    }
}

// ---------------- padded offsets (256-multiple) + pair prefill ----------------
__global__ __launch_bounds__(256) void k_offs(const int* __restrict__ cnt,
                                              int* __restrict__ cnt_pad, int* __restrict__ off_pad,
                                              int* __restrict__ pair_tok, float* __restrict__ pair_w) {
    if (threadIdx.x == 0) {
        int o = 0;
        for (int e = 0; e < NEXP; ++e) {
            int cp = ((cnt[e] + 255) >> 8) << 8;
            cnt_pad[e] = cp; off_pad[e] = o; o += cp;
        }
    }
    for (int i = threadIdx.x; i < PAIR_CAP; i += 256) { pair_tok[i] = 0; pair_w[i] = 0.f; }
}

__global__ __launch_bounds__(256) void k_place(const int* __restrict__ te, const float* __restrict__ tw,
                                               const int* __restrict__ off_pad, int* __restrict__ cur,
                                               int* __restrict__ pair_tok, float* __restrict__ pair_w, int n) {
    int t = blockIdx.x * 256 + threadIdx.x;
    if (t >= n) return;
#pragma unroll
    for (int j = 0; j < 2; ++j) {
        int e = te[2*t+j];
        int idx = atomicAdd(&cur[e], 1);
        int slot = off_pad[e] + idx;
        pair_tok[slot] = t; pair_w[slot] = tw[2*t+j];
    }
}

// ---------------- cvt1: W1 fp32 [e][1024k][4096f] -> W1T_h bf16 [e][2048n][1024k] ----------------
__global__ __launch_bounds__(256) void k_cvt1(const float* __restrict__ W1,
                                              unsigned short* __restrict__ WT, int h) {
    __shared__ float lt[64][65];
    int e = blockIdx.z, nt = blockIdx.y, kt = blockIdx.x;
    int col0 = (nt < 16) ? (h * 1024 + nt * 64) : (FF + h * 1024 + (nt - 16) * 64);
    const float* src = W1 + (size_t)e * DM * F2 + (size_t)(kt * 64) * F2 + col0;
    int t = threadIdx.x;
#pragma unroll
    for (int i = 0; i < 4; ++i) {
        int flat = i * 256 + t;
        int k = flat >> 4, c4 = (flat & 15) * 4;
        float4 v = *(const float4*)(src + (size_t)k * F2 + c4);
        lt[k][c4] = v.x; lt[k][c4+1] = v.y; lt[k][c4+2] = v.z; lt[k][c4+3] = v.w;
    }
    __syncthreads();
    unsigned short* dst = WT + ((size_t)e * 2048 + nt * 64) * 1024 + kt * 64;
#pragma unroll
    for (int i = 0; i < 4; ++i) {
        int flat = i * 256 + t;
        int n = flat >> 4, kc = (flat & 15) * 4;
        unsigned int lo = (unsigned int)bf16_rne(lt[kc][n])   | ((unsigned int)bf16_rne(lt[kc+1][n]) << 16);
        unsigned int hi = (unsigned int)bf16_rne(lt[kc+2][n]) | ((unsigned int)bf16_rne(lt[kc+3][n]) << 16);
        *(uint2*)(dst + (size_t)n * 1024 + kc) = make_uint2(lo, hi);
    }
}

// ---------------- cvt2: W2 fp32 [e][2048k][1024d] -> W2T bf16 [e][1024n][2048k] ----------------
__global__ __launch_bounds__(256) void k_cvt2(const float* __restrict__ W2,
                                              unsigned short* __restrict__ WT) {
    __shared__ float lt[64][65];
    int e = blockIdx.z, nt = blockIdx.y, kt = blockIdx.x;
    const float* src = W2 + (size_t)e * FF * DM + (size_t)(kt * 64) * DM + nt * 64;
    int t = threadIdx.x;
#pragma unroll
    for (int i = 0; i < 4; ++i) {
        int flat = i * 256 + t;
        int k = flat >> 4, c4 = (flat & 15) * 4;
        float4 v = *(const float4*)(src + (size_t)k * DM + c4);
        lt[k][c4] = v.x; lt[k][c4+1] = v.y; lt[k][c4+2] = v.z; lt[k][c4+3] = v.w;
    }
    __syncthreads();
    unsigned short* dst = WT + ((size_t)e * 1024 + nt * 64) * 2048 + kt * 64;
#pragma unroll
    for (int i = 0; i < 4; ++i) {
        int flat = i * 256 + t;
        int n = flat >> 4, kc = (flat & 15) * 4;
        unsigned int lo = (unsigned int)bf16_rne(lt[kc][n])   | ((unsigned int)bf16_rne(lt[kc+1][n]) << 16);
        unsigned int hi = (unsigned int)bf16_rne(lt[kc+2][n]) | ((unsigned int)bf16_rne(lt[kc+3][n]) << 16);
        *(uint2*)(dst + (size_t)n * 2048 + kc) = make_uint2(lo, hi);
    }
}

// ============ 8-phase-style GEMM core macros (2 phases per 64-K tile) ============
// LDS: A [2][256][64] bf16 (64KB) + B [2][128][64] (32KB). 8 waves = 2M x 4N.
// Wave output 128 rows x 32 B-rows. Per phase: 16 MFMA.
// Stage units: 64 rows per gload16 (wave base = u*64 + w*8). 6 gloads/K-tile (4A+2B).
// Free-timeline per K-tile j (slot sl): B + A(u0,u2) free after ph0; A(u1,u3) after ph1.
// Stages: j.ph0 -> A(j+1){u1,u3} (slot sl^1); j.ph1 -> B(j+2){u0,u1}+A(j+2){u0,u2} (slot sl).
// vmcnt(4) at j.ph1 end (before last barrier) guarantees KT j+1 fully in LDS for (j+1).ph0.

#define GEMM_SETUP() \
    int t = threadIdx.x, w = t >> 6, l = t & 63; \
    int wm = w >> 2, wn = w & 3; \
    int lr = l & 15, kg = l >> 4; \
    int xorv = (lr & 7) << 4; \
    int kb0 = (kg * 16) ^ xorv; \
    int kb1 = (64 + kg * 16) ^ xorv; \
    int c8 = ((l & 7) ^ (l >> 3)) * 8; \
    int abase[8], bbase[2]; \
    _Pragma("unroll") for (int m = 0; m < 8; ++m) abase[m] = (wm * 128 + m * 16 + lr) * 128; \
    _Pragma("unroll") for (int nn = 0; nn < 2; ++nn) bbase[nn] = (wn * 32 + nn * 16 + lr) * 128;

#define STA(u, kt, sl) gload16(asrc[u] + (size_t)(kt) * 64, lA + ((sl) << 14) + aoff[u])
#define STB(u, kt, sl) gload16(bsrc[u] + (size_t)(kt) * 64, lB + ((sl) << 13) + boff[u])

#define PH0_READS() \
    _Pragma("unroll") for (int nn = 0; nn < 2; ++nn) { \
        bfr[nn][0] = *(const bf16x8*)(cB + slBb + bbase[nn] + kb0); \
        bfr[nn][1] = *(const bf16x8*)(cB + slBb + bbase[nn] + kb1); \
    } \
    _Pragma("unroll") for (int mm = 0; mm < 4; ++mm) { \
        af[mm][0] = *(const bf16x8*)(cA + slAb + abase[mm] + kb0); \
        af[mm][1] = *(const bf16x8*)(cA + slAb + abase[mm] + kb1); \
    }

#define PH1_READS() \
    _Pragma("unroll") for (int mm = 0; mm < 4; ++mm) { \
        af[mm][0] = *(const bf16x8*)(cA + slAb + abase[4 + mm] + kb0); \
        af[mm][1] = *(const bf16x8*)(cA + slAb + abase[4 + mm] + kb1); \
    }

#define MFMA16x(mo) \
    _Pragma("unroll") for (int mm = 0; mm < 4; ++mm) \
    _Pragma("unroll") for (int nn = 0; nn < 2; ++nn) { \
        acc[(mo) + mm][nn] = MFMA16(af[mm][0], bfr[nn][0], acc[(mo) + mm][nn]); \
        acc[(mo) + mm][nn] = MFMA16(af[mm][1], bfr[nn][1], acc[(mo) + mm][nn]); \
    }

#define GEMM_KLOOP(NKT) \
    STB(0, 0, 0); STB(1, 0, 0); STA(0, 0, 0); STA(1, 0, 0); STA(2, 0, 0); STA(3, 0, 0); \
    STB(0, 1, 1); STB(1, 1, 1); STA(0, 1, 1); STA(2, 1, 1); \
    WAIT_VM(4); \
    BARRIER(); \
    for (int j = 0; j < (NKT); ++j) { \
        int sl = j & 1; \
        int slAb = sl << 15, slBb = sl << 14; \
        bf16x8 bfr[2][2], af[4][2]; \
        PH0_READS(); \
        if (j + 1 < (NKT)) { STA(1, j + 1, sl ^ 1); STA(3, j + 1, sl ^ 1); } \
        BARRIER(); \
        WAIT_LGKM0(); \
        __builtin_amdgcn_s_setprio(1); \
        MFMA16x(0); \
        __builtin_amdgcn_s_setprio(0); \
        BARRIER(); \
        PH1_READS(); \
        if (j + 2 < (NKT)) { STB(0, j + 2, sl); STB(1, j + 2, sl); STA(0, j + 2, sl); STA(2, j + 2, sl); } \
        BARRIER(); \
        WAIT_LGKM0(); \
        __builtin_amdgcn_s_setprio(1); \
        MFMA16x(4); \
        __builtin_amdgcn_s_setprio(0); \
        if (j + 1 < (NKT)) { if (j + 2 < (NKT)) { WAIT_VM(4); } else { WAIT_VM(0); } } \
        BARRIER(); \
    }

// ---------------- GEMM1: 256 rows x 64 hh-cols (128 B-rows a/g interleaved) ----------------
// grid 4096 (XCD-chunked, active ~512): c0t=lid&15, yt=(lid>>4)&31, e=lid>>9
__global__ __launch_bounds__(512, 1) void k_gemm1(const unsigned short* __restrict__ xbf,
                                                  const unsigned short* __restrict__ W1T,
                                                  const float* __restrict__ b1,
                                                  const int* __restrict__ pair_tok,
                                                  const int* __restrict__ cnt_pad,
                                                  const int* __restrict__ off_pad,
                                                  unsigned short* __restrict__ hh, int h) {
    int id = blockIdx.x;
    int lid = (id & 7) * 512 + (id >> 3);
    int c0t = lid & 15, yt = (lid >> 4) & 31, e = lid >> 9;
    if (yt * 256 >= cnt_pad[e]) return;
    int row0 = off_pad[e] + yt * 256;
    int c0 = c0t * 64;
    const unsigned short* WTe = W1T + (size_t)e * 2048 * 1024;

    extern __shared__ unsigned char smem[];
    unsigned short* lA = (unsigned short*)smem;             // [2][256][64]
    unsigned short* lB = (unsigned short*)(smem + 65536);   // [2][128][64]
    const unsigned char* cA = smem;
    const unsigned char* cB = smem + 65536;

    GEMM_SETUP();

    const unsigned short* asrc[4];
    const unsigned short* bsrc[2];
    int aoff[4], boff[2];
#pragma unroll
    for (int u = 0; u < 4; ++u) {
        int r = u * 64 + w * 8 + (l >> 3);
        int tok = pair_tok[row0 + r];
        asrc[u] = xbf + (size_t)tok * DM + c8;
        aoff[u] = (u * 64 + w * 8) * 64;
    }
#pragma unroll
    for (int u = 0; u < 2; ++u) {
        int r = u * 64 + w * 8 + (l >> 3);
        // B-row r -> hh-col (c0 + (r>>5)*16 + (r&15)), a (r bit4=0) or g (bit4=1)
        int bn = ((r >> 4) & 1) * 1024 + c0 + (r >> 5) * 16 + (r & 15);
        bsrc[u] = WTe + (size_t)bn * 1024 + c8;
        boff[u] = (u * 64 + w * 8) * 64;
    }

    f32x4 acc[8][2];
#pragma unroll
    for (int m = 0; m < 8; ++m) { acc[m][0] = (f32x4){0,0,0,0}; acc[m][1] = (f32x4){0,0,0,0}; }

    GEMM_KLOOP(16);

    // epilogue: SwiGLU; acc[m][0]=a, acc[m][1]=g, col = c0 + wn*16 + lr
    int colh = h * 1024 + c0 + wn * 16 + lr;
    float ba1 = b1[e * F2 + colh], bg1 = b1[e * F2 + FF + colh];
#pragma unroll
    for (int m = 0; m < 8; ++m)
#pragma unroll
        for (int jj = 0; jj < 4; ++jj) {
            int row = wm * 128 + m * 16 + kg * 4 + jj;
            float a = acc[m][0][jj] + ba1;
            float g = acc[m][1][jj] + bg1;
            float sg = a / (1.f + __expf(-a)) * g;
            hh[(size_t)(row0 + row) * FF + colh] = bf16_rne(sg);
        }
}

// ---------------- GEMM2: 256 rows x 128 d-cols ----------------
// grid 2048 (XCD-chunked, active ~256): d0t=lid&7, yt=(lid>>3)&31, e=lid>>8
__global__ __launch_bounds__(512, 1) void k_gemm2(const unsigned short* __restrict__ hh,
                                                  const unsigned short* __restrict__ W2T,
                                                  const float* __restrict__ b2,
                                                  const int* __restrict__ pair_tok,
                                                  const float* __restrict__ pair_w,
                                                  const int* __restrict__ cnt_pad,
                                                  const int* __restrict__ off_pad,
                                                  float* __restrict__ out) {
    int id = blockIdx.x;
    int lid = (id & 7) * 256 + (id >> 3);
    int d0t = lid & 7, yt = (lid >> 3) & 31, e = lid >> 8;
    if (yt * 256 >= cnt_pad[e]) return;
    int row0 = off_pad[e] + yt * 256;
    int d0 = d0t * 128;
    const unsigned short* WTe = W2T + (size_t)e * 1024 * 2048;

    extern __shared__ unsigned char smem[];
    unsigned short* lA = (unsigned short*)smem;
    unsigned short* lB = (unsigned short*)(smem + 65536);
    const unsigned char* cA = smem;
    const unsigned char* cB = smem + 65536;

    GEMM_SETUP();

    const unsigned short* asrc[4];
    const unsigned short* bsrc[2];
    int aoff[4], boff[2];
#pragma unroll
    for (int u = 0; u < 4; ++u) {
        int r = u * 64 + w * 8 + (l >> 3);
        asrc[u] = hh + (size_t)(row0 + r) * FF + c8;
        aoff[u] = (u * 64 + w * 8) * 64;
    }
#pragma unroll
    for (int u = 0; u < 2; ++u) {
        int r = u * 64 + w * 8 + (l >> 3);
        bsrc[u] = WTe + (size_t)(d0 + r) * 2048 + c8;
        boff[u] = (u * 64 + w * 8) * 64;
    }

    f32x4 acc[8][2];
#pragma unroll
    for (int m = 0; m < 8; ++m) { acc[m][0] = (f32x4){0,0,0,0}; acc[m][1] = (f32x4){0,0,0,0}; }

    GEMM_KLOOP(32);

    // epilogue: weighted atomic combine
#pragma unroll
    for (int nn = 0; nn < 2; ++nn) {
        int col = d0 + wn * 32 + nn * 16 + lr;
        float b2v = b2[e * DM + col];
#pragma unroll
        for (int m = 0; m < 8; ++m)
#pragma unroll
            for (int jj = 0; jj < 4; ++jj) {
                int row = wm * 128 + m * 16 + kg * 4 + jj;
                int pr = row0 + row;
                int tok = pair_tok[pr];
                float wt = pair_w[pr];
                atomicAdd(out + (size_t)tok * DM + col, wt * (acc[m][nn][jj] + b2v));
            }
    }
}

// ---------------- host ----------------
extern "C" void kernel_launch(void* const* d_in, const int* in_sizes, int n_in,
                              void* d_out, int out_size, void* d_ws, size_t ws_size,
                              hipStream_t stream) {
    const float* x  = (const float*)d_in[0];
    const float* Wg = (const float*)d_in[1];
    const float* W1 = (const float*)d_in[2];
    const float* b1 = (const float*)d_in[3];
    const float* W2 = (const float*)d_in[4];
    const float* b2 = (const float*)d_in[5];
    float* out = (float*)d_out;

    char* ws = (char*)d_ws;
    unsigned short* xbf = (unsigned short*)ws;                        // 8.39 MB
    unsigned short* hh  = (unsigned short*)(ws + 8388608);            // 41.94 MB (10240 rows)
    unsigned short* WT  = (unsigned short*)(ws + 50331648);           // 33.55 MB (W1T half / W2T shared)
    int*   pair_tok = (int*)(ws + 83886080);
    float* pair_w   = (float*)(ws + 83927040);
    int*   te       = (int*)(ws + 83968000);
    float* tw       = (float*)(ws + 84000768);
    int*   cnt      = (int*)(ws + 84033536);
    int*   cur      = (int*)(ws + 84033568);
    int*   cnt_pad  = (int*)(ws + 84033600);
    int*   off_pad  = (int*)(ws + 84033632);

    hipMemsetAsync(d_out, 0, (size_t)out_size * sizeof(float), stream);
    hipMemsetAsync(cnt, 0, 64, stream);  // cnt + cur

    k_gate<<<NTOK, 64, 0, stream>>>(x, Wg, xbf, te, tw, cnt);
    k_offs<<<1, 256, 0, stream>>>(cnt, cnt_pad, off_pad, pair_tok, pair_w);
    k_place<<<(NTOK + 255) / 256, 256, 0, stream>>>(te, tw, off_pad, cur, pair_tok, pair_w, NTOK);

    for (int h = 0; h < 2; ++h) {
        k_cvt1<<<dim3(16, 32, 8), 256, 0, stream>>>(W1, WT, h);
        k_gemm1<<<4096, 512, 98304, stream>>>(xbf, WT, b1, pair_tok, cnt_pad, off_pad, hh, h);
    }
    k_cvt2<<<dim3(32, 16, 8), 256, 0, stream>>>(W2, WT);
    k_gemm2<<<2048, 512, 98304, stream>>>(hh, WT, b2, pair_tok, pair_w, cnt_pad, off_pad, out);
}

// Round 10
// 359.922 us; speedup vs baseline: 1.3882x; 1.3882x over previous
//
#include <hip/hip_runtime.h>
#include <hip/hip_bf16.h>
#include <stdint.h>

#define NTOK 4096
#define DM 1024
#define FF 2048
#define F2 4096
#define NEXP 8
#define PAIR_CAP 10240

typedef __bf16 bf16x8 __attribute__((ext_vector_type(8)));
typedef float f32x4 __attribute__((ext_vector_type(4)));

__device__ __forceinline__ unsigned short bf16_rne(float f) {
    union { float f; unsigned int u; } v; v.f = f;
    unsigned int u = v.u;
    return (unsigned short)((u + 0x7FFFu + ((u >> 16) & 1u)) >> 16);
}

__device__ __forceinline__ f32x4 MFMA16(bf16x8 a, bf16x8 b, f32x4 c) {
    return __builtin_amdgcn_mfma_f32_16x16x32_bf16(a, b, c, 0, 0, 0);
}

__device__ __forceinline__ void gload16(const void* g, void* l) {
    __builtin_amdgcn_global_load_lds(
        (const __attribute__((address_space(1))) uint32_t*)g,
        (__attribute__((address_space(3))) uint32_t*)l, 16, 0, 0);
}

// ---------------- gating: scores (fp32), top-2 softmax, x -> bf16 ----------------
__global__ __launch_bounds__(64) void k_gate(const float* __restrict__ x,
                                             const float* __restrict__ Wg,
                                             unsigned short* __restrict__ xbf,
                                             int* __restrict__ te, float* __restrict__ tw,
                                             int* __restrict__ cnt) {
    int t = blockIdx.x;
    int l = threadIdx.x;
    const float* xr = x + (size_t)t * DM + l * 16;
    float xv[16];
#pragma unroll
    for (int i = 0; i < 4; ++i) {
        float4 v = ((const float4*)xr)[i];
        xv[4*i+0] = v.x; xv[4*i+1] = v.y; xv[4*i+2] = v.z; xv[4*i+3] = v.w;
    }
    unsigned int pk[8];
#pragma unroll
    for (int i = 0; i < 8; ++i)
        pk[i] = (unsigned int)bf16_rne(xv[2*i]) | ((unsigned int)bf16_rne(xv[2*i+1]) << 16);
    uint4* dst = (uint4*)(xbf + (size_t)t * DM + l * 16);
    dst[0] = make_uint4(pk[0], pk[1], pk[2], pk[3]);
    dst[1] = make_uint4(pk[4], pk[5], pk[6], pk[7]);

    float s[NEXP];
#pragma unroll
    for (int e = 0; e < NEXP; ++e) {
        const float* wr = Wg + e * DM + l * 16;
        float acc = 0.f;
#pragma unroll
        for (int i = 0; i < 4; ++i) {
            float4 v = ((const float4*)wr)[i];
            acc += v.x * xv[4*i] + v.y * xv[4*i+1] + v.z * xv[4*i+2] + v.w * xv[4*i+3];
        }
        s[e] = acc;
    }
#pragma unroll
    for (int off = 32; off > 0; off >>= 1) {
#pragma unroll
        for (int e = 0; e < NEXP; ++e) s[e] += __shfl_xor(s[e], off, 64);
    }
    if (l == 0) {
        int e0 = 0; float v0 = s[0];
        for (int e = 1; e < NEXP; ++e) if (s[e] > v0) { v0 = s[e]; e0 = e; }
        int e1 = -1; float v1 = -1e30f;
        for (int e = 0; e < NEXP; ++e) if (e != e0 && s[e] > v1) { v1 = s[e]; e1 = e; }
        float w0 = 1.f / (1.f + __expf(v1 - v0));
        float w1 = 1.f - w0;
        te[2*t] = e0; te[2*t+1] = e1;
        tw[2*t] = w0; tw[2*t+1] = w1;
        atomicAdd(&cnt[e0], 1); atomicAdd(&cnt[e1], 1);
    }
}

// ---------------- padded offsets (128-multiple) + pair prefill ----------------
__global__ __launch_bounds__(256) void k_offs(const int* __restrict__ cnt,
                                              int* __restrict__ cnt_pad, int* __restrict__ off_pad,
                                              int* __restrict__ pair_tok, float* __restrict__ pair_w) {
    if (threadIdx.x == 0) {
        int o = 0;
        for (int e = 0; e < NEXP; ++e) {
            int cp = ((cnt[e] + 127) >> 7) << 7;
            cnt_pad[e] = cp; off_pad[e] = o; o += cp;
        }
    }
    for (int i = threadIdx.x; i < PAIR_CAP; i += 256) { pair_tok[i] = 0; pair_w[i] = 0.f; }
}

__global__ __launch_bounds__(256) void k_place(const int* __restrict__ te, const float* __restrict__ tw,
                                               const int* __restrict__ off_pad, int* __restrict__ cur,
                                               int* __restrict__ pair_tok, float* __restrict__ pair_w,
                                               int* __restrict__ slot_of, int n) {
    int t = blockIdx.x * 256 + threadIdx.x;
    if (t >= n) return;
#pragma unroll
    for (int j = 0; j < 2; ++j) {
        int e = te[2*t+j];
        int idx = atomicAdd(&cur[e], 1);
        int slot = off_pad[e] + idx;
        pair_tok[slot] = t; pair_w[slot] = tw[2*t+j];
        slot_of[2*t+j] = slot;
    }
}

// ---------------- cvt1: W1 fp32 -> W1T_h bf16 [e][2048n][1024k] ----------------
__global__ __launch_bounds__(256) void k_cvt1(const float* __restrict__ W1,
                                              unsigned short* __restrict__ WT, int h) {
    __shared__ float lt[64][65];
    int e = blockIdx.z, nt = blockIdx.y, kt = blockIdx.x;
    int col0 = (nt < 16) ? (h * 1024 + nt * 64) : (FF + h * 1024 + (nt - 16) * 64);
    const float* src = W1 + (size_t)e * DM * F2 + (size_t)(kt * 64) * F2 + col0;
    int t = threadIdx.x;
#pragma unroll
    for (int i = 0; i < 4; ++i) {
        int flat = i * 256 + t;
        int k = flat >> 4, c4 = (flat & 15) * 4;
        float4 v = *(const float4*)(src + (size_t)k * F2 + c4);
        lt[k][c4] = v.x; lt[k][c4+1] = v.y; lt[k][c4+2] = v.z; lt[k][c4+3] = v.w;
    }
    __syncthreads();
    unsigned short* dst = WT + ((size_t)e * 2048 + nt * 64) * 1024 + kt * 64;
#pragma unroll
    for (int i = 0; i < 4; ++i) {
        int flat = i * 256 + t;
        int n = flat >> 4, kc = (flat & 15) * 4;
        unsigned int lo = (unsigned int)bf16_rne(lt[kc][n])   | ((unsigned int)bf16_rne(lt[kc+1][n]) << 16);
        unsigned int hi = (unsigned int)bf16_rne(lt[kc+2][n]) | ((unsigned int)bf16_rne(lt[kc+3][n]) << 16);
        *(uint2*)(dst + (size_t)n * 1024 + kc) = make_uint2(lo, hi);
    }
}

// ---------------- cvt2: W2 fp32 -> W2T bf16 [e][1024n][2048k] ----------------
__global__ __launch_bounds__(256) void k_cvt2(const float* __restrict__ W2,
                                              unsigned short* __restrict__ WT) {
    __shared__ float lt[64][65];
    int e = blockIdx.z, nt = blockIdx.y, kt = blockIdx.x;
    const float* src = W2 + (size_t)e * FF * DM + (size_t)(kt * 64) * DM + nt * 64;
    int t = threadIdx.x;
#pragma unroll
    for (int i = 0; i < 4; ++i) {
        int flat = i * 256 + t;
        int k = flat >> 4, c4 = (flat & 15) * 4;
        float4 v = *(const float4*)(src + (size_t)k * DM + c4);
        lt[k][c4] = v.x; lt[k][c4+1] = v.y; lt[k][c4+2] = v.z; lt[k][c4+3] = v.w;
    }
    __syncthreads();
    unsigned short* dst = WT + ((size_t)e * 1024 + nt * 64) * 2048 + kt * 64;
#pragma unroll
    for (int i = 0; i < 4; ++i) {
        int flat = i * 256 + t;
        int n = flat >> 4, kc = (flat & 15) * 4;
        unsigned int lo = (unsigned int)bf16_rne(lt[kc][n])   | ((unsigned int)bf16_rne(lt[kc+1][n]) << 16);
        unsigned int hi = (unsigned int)bf16_rne(lt[kc+2][n]) | ((unsigned int)bf16_rne(lt[kc+3][n]) << 16);
        *(uint2*)(dst + (size_t)n * 2048 + kc) = make_uint2(lo, hi);
    }
}

// ---------------- GEMM1: R3-proven structure, 128 rows x 64 hh-cols, 4 waves, 32KB ----------------
// grid 4096 XCD-chunked; active 1024 = 4/CU
__global__ __launch_bounds__(256, 4) void k_gemm1(const unsigned short* __restrict__ xbf,
                                                  const unsigned short* __restrict__ W1T,
                                                  const float* __restrict__ b1,
                                                  const int* __restrict__ pair_tok,
                                                  const int* __restrict__ cnt_pad,
                                                  const int* __restrict__ off_pad,
                                                  unsigned short* __restrict__ hh, int h) {
    int id = blockIdx.x;
    int lid = (id & 7) * 512 + (id >> 3);
    int c0t = lid & 15, yt = (lid >> 4) & 31, e = lid >> 9;
    if (yt * 128 >= cnt_pad[e]) return;
    int row0 = off_pad[e] + yt * 128;
    int c0 = c0t * 64;
    const unsigned short* WTe = W1T + (size_t)e * 2048 * 1024;

    __shared__ unsigned short lA[128 * 64];
    __shared__ unsigned short lB[128 * 64];

    int t = threadIdx.x, w = t >> 6, l = t & 63;
    int wm = w >> 1, wn = w & 1;

    const unsigned short* asrc[4];
    const unsigned short* bsrc[4];
    unsigned short* adst[4];
    unsigned short* bdst[4];
    int c8 = ((l & 7) ^ (l >> 3)) * 8;
#pragma unroll
    for (int q = 0; q < 4; ++q) {
        int r = w * 32 + q * 8 + (l >> 3);
        int tok = pair_tok[row0 + r];
        asrc[q] = xbf + (size_t)tok * DM + c8;
        adst[q] = lA + (w * 32 + q * 8) * 64;
        int bn = (r < 64) ? (c0 + r) : (1024 + c0 + (r - 64));
        bsrc[q] = WTe + (size_t)bn * 1024 + c8;
        bdst[q] = lB + (w * 32 + q * 8) * 64;
    }

    f32x4 aca[4][2], acg[4][2];
#pragma unroll
    for (int m = 0; m < 4; ++m)
#pragma unroll
        for (int fn = 0; fn < 2; ++fn) { aca[m][fn] = (f32x4){0,0,0,0}; acg[m][fn] = (f32x4){0,0,0,0}; }

#pragma unroll
    for (int q = 0; q < 4; ++q) { gload16(asrc[q], adst[q]); gload16(bsrc[q], bdst[q]); }

    int lr = l & 15, kg = l >> 4;
    for (int kt = 0; kt < 16; ++kt) {
        __syncthreads();
#pragma unroll
        for (int ks = 0; ks < 2; ++ks) {
            int kc = ks * 64 + kg * 16;
            bf16x8 af[4];
#pragma unroll
            for (int m = 0; m < 4; ++m) {
                int row = wm * 64 + m * 16 + lr;
                af[m] = *(const bf16x8*)((const char*)lA + row * 128 + (kc ^ ((row & 7) << 4)));
            }
#pragma unroll
            for (int fn = 0; fn < 2; ++fn) {
                int na = wn * 32 + fn * 16 + lr;
                bf16x8 ba = *(const bf16x8*)((const char*)lB + na * 128 + (kc ^ ((na & 7) << 4)));
                bf16x8 bg = *(const bf16x8*)((const char*)lB + (na + 64) * 128 + (kc ^ ((na & 7) << 4)));
#pragma unroll
                for (int m = 0; m < 4; ++m) {
                    aca[m][fn] = MFMA16(af[m], ba, aca[m][fn]);
                    acg[m][fn] = MFMA16(af[m], bg, acg[m][fn]);
                }
            }
        }
        __syncthreads();
        if (kt < 15) {
#pragma unroll
            for (int q = 0; q < 4; ++q) {
                gload16(asrc[q] + (kt + 1) * 64, adst[q]);
                gload16(bsrc[q] + (kt + 1) * 64, bdst[q]);
            }
        }
    }
#pragma unroll
    for (int m = 0; m < 4; ++m)
#pragma unroll
        for (int fn = 0; fn < 2; ++fn) {
            int colh = h * 1024 + c0 + wn * 32 + fn * 16 + lr;
            float ba1 = b1[e * F2 + colh], bg1 = b1[e * F2 + FF + colh];
#pragma unroll
            for (int j = 0; j < 4; ++j) {
                int row = wm * 64 + m * 16 + kg * 4 + j;
                float a = aca[m][fn][j] + ba1;
                float g = acg[m][fn][j] + bg1;
                float sg = a / (1.f + __expf(-a)) * g;
                hh[(size_t)(row0 + row) * FF + colh] = bf16_rne(sg);
            }
        }
}

// ---------------- GEMM2: 128 rows x 64 d-cols, 4 waves, 24KB LDS, no atomics (eo mode) ----------------
// grid 4096 XCD-chunked; active 1024 = 4/CU. MODE 0: store wt*acc to eo. MODE 1: atomicAdd out.
__global__ __launch_bounds__(256, 4) void k_gemm2(const unsigned short* __restrict__ hh,
                                                  const unsigned short* __restrict__ W2T,
                                                  const float* __restrict__ b2,
                                                  const int* __restrict__ pair_tok,
                                                  const float* __restrict__ pair_w,
                                                  const int* __restrict__ cnt_pad,
                                                  const int* __restrict__ off_pad,
                                                  float* __restrict__ eo_or_out, int mode) {
    int id = blockIdx.x;
    int lid = (id & 7) * 512 + (id >> 3);
    int d0t = lid & 15, yt = (lid >> 4) & 31, e = lid >> 9;
    if (yt * 128 >= cnt_pad[e]) return;
    int row0 = off_pad[e] + yt * 128;
    int d0 = d0t * 64;
    const unsigned short* WTe = W2T + (size_t)e * 1024 * 2048;

    __shared__ unsigned short lA[128 * 64];
    __shared__ unsigned short lB[64 * 64];

    int t = threadIdx.x, w = t >> 6, l = t & 63;
    int wm = w >> 1, wn = w & 1;

    const unsigned short* asrc[4];
    const unsigned short* bsrc[2];
    unsigned short* adst[4];
    unsigned short* bdst[2];
    int c8 = ((l & 7) ^ (l >> 3)) * 8;
#pragma unroll
    for (int q = 0; q < 4; ++q) {
        int r = w * 32 + q * 8 + (l >> 3);
        asrc[q] = hh + (size_t)(row0 + r) * FF + c8;
        adst[q] = lA + (w * 32 + q * 8) * 64;
    }
#pragma unroll
    for (int q = 0; q < 2; ++q) {
        int r = w * 16 + q * 8 + (l >> 3);   // 64 B-rows
        bsrc[q] = WTe + (size_t)(d0 + r) * 2048 + c8;
        bdst[q] = lB + (w * 16 + q * 8) * 64;
    }

    f32x4 ac[4][2];
#pragma unroll
    for (int m = 0; m < 4; ++m)
#pragma unroll
        for (int fn = 0; fn < 2; ++fn) ac[m][fn] = (f32x4){0,0,0,0};

#pragma unroll
    for (int q = 0; q < 4; ++q) gload16(asrc[q], adst[q]);
#pragma unroll
    for (int q = 0; q < 2; ++q) gload16(bsrc[q], bdst[q]);

    int lr = l & 15, kg = l >> 4;
    for (int kt = 0; kt < 32; ++kt) {
        __syncthreads();
#pragma unroll
        for (int ks = 0; ks < 2; ++ks) {
            int kc = ks * 64 + kg * 16;
            bf16x8 af[4];
#pragma unroll
            for (int m = 0; m < 4; ++m) {
                int row = wm * 64 + m * 16 + lr;
                af[m] = *(const bf16x8*)((const char*)lA + row * 128 + (kc ^ ((row & 7) << 4)));
            }
#pragma unroll
            for (int fn = 0; fn < 2; ++fn) {
                int n = wn * 32 + fn * 16 + lr;
                bf16x8 bb = *(const bf16x8*)((const char*)lB + n * 128 + (kc ^ ((n & 7) << 4)));
#pragma unroll
                for (int m = 0; m < 4; ++m) ac[m][fn] = MFMA16(af[m], bb, ac[m][fn]);
            }
        }
        __syncthreads();
        if (kt < 31) {
#pragma unroll
            for (int q = 0; q < 4; ++q) gload16(asrc[q] + (kt + 1) * 64, adst[q]);
#pragma unroll
            for (int q = 0; q < 2; ++q) gload16(bsrc[q] + (kt + 1) * 64, bdst[q]);
        }
    }

    if (mode == 0) {
        // store wt*acc to eo[pr][col] (plain coalesced fp32 stores; bias folded in combine)
#pragma unroll
        for (int m = 0; m < 4; ++m)
#pragma unroll
            for (int fn = 0; fn < 2; ++fn) {
                int col = d0 + wn * 32 + fn * 16 + lr;
#pragma unroll
                for (int j = 0; j < 4; ++j) {
                    int row = wm * 64 + m * 16 + kg * 4 + j;
                    int pr = row0 + row;
                    eo_or_out[(size_t)pr * DM + col] = pair_w[pr] * ac[m][fn][j];
                }
            }
    } else {
#pragma unroll
        for (int m = 0; m < 4; ++m)
#pragma unroll
            for (int fn = 0; fn < 2; ++fn) {
                int col = d0 + wn * 32 + fn * 16 + lr;
                float b2v = b2[e * DM + col];
#pragma unroll
                for (int j = 0; j < 4; ++j) {
                    int row = wm * 64 + m * 16 + kg * 4 + j;
                    int pr = row0 + row;
                    atomicAdd(eo_or_out + (size_t)pair_tok[pr] * DM + col,
                              pair_w[pr] * (ac[m][fn][j] + b2v));
                }
            }
    }
}

// ---------------- combine: out[t] = eo[s0]+eo[s1] + w0*b2[e0] + w1*b2[e1] ----------------
__global__ __launch_bounds__(256) void k_comb(const float* __restrict__ eo,
                                              const int* __restrict__ slot_of,
                                              const int* __restrict__ te,
                                              const float* __restrict__ tw,
                                              const float* __restrict__ b2,
                                              float* __restrict__ out) {
    int t = blockIdx.x;
    int d = threadIdx.x * 4;
    int s0 = slot_of[2*t], s1 = slot_of[2*t+1];
    int e0 = te[2*t], e1 = te[2*t+1];
    float w0 = tw[2*t], w1 = tw[2*t+1];
    float4 a = *(const float4*)(eo + (size_t)s0 * DM + d);
    float4 b = *(const float4*)(eo + (size_t)s1 * DM + d);
    float4 p = *(const float4*)(b2 + (size_t)e0 * DM + d);
    float4 q = *(const float4*)(b2 + (size_t)e1 * DM + d);
    float4 r;
    r.x = a.x + b.x + w0 * p.x + w1 * q.x;
    r.y = a.y + b.y + w0 * p.y + w1 * q.y;
    r.z = a.z + b.z + w0 * p.z + w1 * q.z;
    r.w = a.w + b.w + w0 * p.w + w1 * q.w;
    *(float4*)(out + (size_t)t * DM + d) = r;
}

// ---------------- host ----------------
extern "C" void kernel_launch(void* const* d_in, const int* in_sizes, int n_in,
                              void* d_out, int out_size, void* d_ws, size_t ws_size,
                              hipStream_t stream) {
    const float* x  = (const float*)d_in[0];
    const float* Wg = (const float*)d_in[1];
    const float* W1 = (const float*)d_in[2];
    const float* b1 = (const float*)d_in[3];
    const float* W2 = (const float*)d_in[4];
    const float* b2 = (const float*)d_in[5];
    float* out = (float*)d_out;

    char* ws = (char*)d_ws;
    unsigned short* xbf = (unsigned short*)ws;                        // 8.39 MB
    unsigned short* hh  = (unsigned short*)(ws + 8388608);            // 41.94 MB
    unsigned short* WT  = (unsigned short*)(ws + 50331648);           // 33.55 MB
    float* eo           = (float*)(ws + 83886080);                    // 37.75 MB (mode 0 only)
    const size_t EO_END = 83886080ull + 37748736ull;                  // 121.6 MB
    const size_t MISC_NEED = 262144;                                  // misc tail
    int mode = (ws_size >= EO_END + MISC_NEED) ? 0 : 1;
    size_t mb = (mode == 0) ? EO_END : 83886080ull;                   // misc base
    int*   pair_tok = (int*)(ws + mb);
    float* pair_w   = (float*)(ws + mb + 40960);
    int*   slot_of  = (int*)(ws + mb + 81920);
    int*   te       = (int*)(ws + mb + 114688);
    float* tw       = (float*)(ws + mb + 147456);
    int*   cnt      = (int*)(ws + mb + 180224);
    int*   cur      = (int*)(ws + mb + 180256);
    int*   cnt_pad  = (int*)(ws + mb + 180288);
    int*   off_pad  = (int*)(ws + mb + 180320);

    if (mode == 1)
        hipMemsetAsync(d_out, 0, (size_t)out_size * sizeof(float), stream);
    hipMemsetAsync(cnt, 0, 64, stream);  // cnt + cur

    k_gate<<<NTOK, 64, 0, stream>>>(x, Wg, xbf, te, tw, cnt);
    k_offs<<<1, 256, 0, stream>>>(cnt, cnt_pad, off_pad, pair_tok, pair_w);
    k_place<<<(NTOK + 255) / 256, 256, 0, stream>>>(te, tw, off_pad, cur, pair_tok, pair_w, slot_of, NTOK);

    for (int h = 0; h < 2; ++h) {
        k_cvt1<<<dim3(16, 32, 8), 256, 0, stream>>>(W1, WT, h);
        k_gemm1<<<4096, 256, 0, stream>>>(xbf, WT, b1, pair_tok, cnt_pad, off_pad, hh, h);
    }
    k_cvt2<<<dim3(32, 16, 8), 256, 0, stream>>>(W2, WT);
    k_gemm2<<<4096, 256, 0, stream>>>(hh, WT, b2, pair_tok, pair_w, cnt_pad, off_pad,
                                      (mode == 0) ? eo : out, mode);
    if (mode == 0)
        k_comb<<<NTOK, 256, 0, stream>>>(eo, slot_of, te, tw, b2, out);
}

// Round 11
// 239.059 us; speedup vs baseline: 2.0900x; 1.5056x over previous
//
#include <hip/hip_runtime.h>
#include <hip/hip_bf16.h>
#include <stdint.h>

#define NTOK 4096
#define DM 1024
#define FF 2048
#define F2 4096
#define NEXP 8
#define PAIR_CAP 10240

typedef __bf16 bf16x8 __attribute__((ext_vector_type(8)));
typedef float f32x4 __attribute__((ext_vector_type(4)));

__device__ __forceinline__ unsigned short bf16_rne(float f) {
    union { float f; unsigned int u; } v; v.f = f;
    unsigned int u = v.u;
    return (unsigned short)((u + 0x7FFFu + ((u >> 16) & 1u)) >> 16);
}

__device__ __forceinline__ f32x4 MFMA16(bf16x8 a, bf16x8 b, f32x4 c) {
    return __builtin_amdgcn_mfma_f32_16x16x32_bf16(a, b, c, 0, 0, 0);
}

__device__ __forceinline__ void gload16(const void* g, void* l) {
    __builtin_amdgcn_global_load_lds(
        (const __attribute__((address_space(1))) uint32_t*)g,
        (__attribute__((address_space(3))) uint32_t*)l, 16, 0, 0);
}

// ---------------- gating: scores (fp32), top-2 softmax, x -> bf16; NO atomics ----------------
__global__ __launch_bounds__(256) void k_gate(const float* __restrict__ x,
                                              const float* __restrict__ Wg,
                                              unsigned short* __restrict__ xbf,
                                              int* __restrict__ te, float* __restrict__ tw) {
    int t = blockIdx.x * 4 + (threadIdx.x >> 6);
    int l = threadIdx.x & 63;
    const float* xr = x + (size_t)t * DM + l * 16;
    float xv[16];
#pragma unroll
    for (int i = 0; i < 4; ++i) {
        float4 v = ((const float4*)xr)[i];
        xv[4*i+0] = v.x; xv[4*i+1] = v.y; xv[4*i+2] = v.z; xv[4*i+3] = v.w;
    }
    unsigned int pk[8];
#pragma unroll
    for (int i = 0; i < 8; ++i)
        pk[i] = (unsigned int)bf16_rne(xv[2*i]) | ((unsigned int)bf16_rne(xv[2*i+1]) << 16);
    uint4* dst = (uint4*)(xbf + (size_t)t * DM + l * 16);
    dst[0] = make_uint4(pk[0], pk[1], pk[2], pk[3]);
    dst[1] = make_uint4(pk[4], pk[5], pk[6], pk[7]);

    float s[NEXP];
#pragma unroll
    for (int e = 0; e < NEXP; ++e) {
        const float* wr = Wg + e * DM + l * 16;
        float acc = 0.f;
#pragma unroll
        for (int i = 0; i < 4; ++i) {
            float4 v = ((const float4*)wr)[i];
            acc += v.x * xv[4*i] + v.y * xv[4*i+1] + v.z * xv[4*i+2] + v.w * xv[4*i+3];
        }
        s[e] = acc;
    }
#pragma unroll
    for (int off = 32; off > 0; off >>= 1) {
#pragma unroll
        for (int e = 0; e < NEXP; ++e) s[e] += __shfl_xor(s[e], off, 64);
    }
    if (l == 0) {
        int e0 = 0; float v0 = s[0];
        for (int e = 1; e < NEXP; ++e) if (s[e] > v0) { v0 = s[e]; e0 = e; }
        int e1 = -1; float v1 = -1e30f;
        for (int e = 0; e < NEXP; ++e) if (e != e0 && s[e] > v1) { v1 = s[e]; e1 = e; }
        float w0 = 1.f / (1.f + __expf(v1 - v0));
        float w1 = 1.f - w0;
        te[2*t] = e0; te[2*t+1] = e1;
        tw[2*t] = w0; tw[2*t+1] = w1;
    }
}

// ---------------- route: deterministic prefix-sum placement, NO atomics, 1 block ----------------
__global__ __launch_bounds__(256) void k_route(const int* __restrict__ te,
                                               const float* __restrict__ tw,
                                               int* __restrict__ pair_tok, float* __restrict__ pair_w,
                                               int* __restrict__ slot_of,
                                               int* __restrict__ cnt_pad, int* __restrict__ off_pad) {
    __shared__ int lc[256][NEXP];   // per-thread counts -> exclusive prefix
    __shared__ int opad[NEXP];
    int t = threadIdx.x;
    // prefill pad arrays (placement overwrites real slots after barriers)
    for (int i = t; i < PAIR_CAP; i += 256) { pair_tok[i] = 0; pair_w[i] = 0.f; }
    // local counts over my 32 pairs (branchless, static indexing)
    int ev[32];
    int c[NEXP];
#pragma unroll
    for (int e = 0; e < NEXP; ++e) c[e] = 0;
#pragma unroll
    for (int j = 0; j < 32; ++j) {
        ev[j] = te[t * 32 + j];
#pragma unroll
        for (int e = 0; e < NEXP; ++e) c[e] += (ev[j] == e) ? 1 : 0;
    }
#pragma unroll
    for (int e = 0; e < NEXP; ++e) lc[t][e] = c[e];
    __syncthreads();
    if (t < NEXP) {   // exclusive prefix per expert
        int run = 0;
        for (int i = 0; i < 256; ++i) { int v = lc[i][t]; lc[i][t] = run; run += v; }
        opad[t] = run;   // total for expert t (temporarily)
    }
    __syncthreads();
    if (t == 0) {
        int o = 0;
        for (int e = 0; e < NEXP; ++e) {
            int tot = opad[e];
            int cp = ((tot + 127) >> 7) << 7;
            cnt_pad[e] = cp; off_pad[e] = o; opad[e] = o; o += cp;
        }
    }
    __syncthreads();
    int cur[NEXP];
#pragma unroll
    for (int e = 0; e < NEXP; ++e) cur[e] = opad[e] + lc[t][e];
#pragma unroll
    for (int j = 0; j < 32; ++j) {
        int p = t * 32 + j;
        int slot = 0;
#pragma unroll
        for (int e = 0; e < NEXP; ++e) {   // branchless conditional cursor bump
            bool m = (ev[j] == e);
            if (m) slot = cur[e];
            cur[e] += m ? 1 : 0;
        }
        pair_tok[slot] = p >> 1;
        pair_w[slot] = tw[p];
        slot_of[p] = slot;
    }
}

// ---------------- cvt1: W1 fp32 -> W1T_h bf16 [e][2048n][1024k] ----------------
__global__ __launch_bounds__(256) void k_cvt1(const float* __restrict__ W1,
                                              unsigned short* __restrict__ WT, int h) {
    __shared__ float lt[64][65];
    int e = blockIdx.z, nt = blockIdx.y, kt = blockIdx.x;
    int col0 = (nt < 16) ? (h * 1024 + nt * 64) : (FF + h * 1024 + (nt - 16) * 64);
    const float* src = W1 + (size_t)e * DM * F2 + (size_t)(kt * 64) * F2 + col0;
    int t = threadIdx.x;
#pragma unroll
    for (int i = 0; i < 4; ++i) {
        int flat = i * 256 + t;
        int k = flat >> 4, c4 = (flat & 15) * 4;
        float4 v = *(const float4*)(src + (size_t)k * F2 + c4);
        lt[k][c4] = v.x; lt[k][c4+1] = v.y; lt[k][c4+2] = v.z; lt[k][c4+3] = v.w;
    }
    __syncthreads();
    unsigned short* dst = WT + ((size_t)e * 2048 + nt * 64) * 1024 + kt * 64;
#pragma unroll
    for (int i = 0; i < 4; ++i) {
        int flat = i * 256 + t;
        int n = flat >> 4, kc = (flat & 15) * 4;
        unsigned int lo = (unsigned int)bf16_rne(lt[kc][n])   | ((unsigned int)bf16_rne(lt[kc+1][n]) << 16);
        unsigned int hi = (unsigned int)bf16_rne(lt[kc+2][n]) | ((unsigned int)bf16_rne(lt[kc+3][n]) << 16);
        *(uint2*)(dst + (size_t)n * 1024 + kc) = make_uint2(lo, hi);
    }
}

// ---------------- cvt2: W2 fp32 -> W2T bf16 [e][1024n][2048k] ----------------
__global__ __launch_bounds__(256) void k_cvt2(const float* __restrict__ W2,
                                              unsigned short* __restrict__ WT) {
    __shared__ float lt[64][65];
    int e = blockIdx.z, nt = blockIdx.y, kt = blockIdx.x;
    const float* src = W2 + (size_t)e * FF * DM + (size_t)(kt * 64) * DM + nt * 64;
    int t = threadIdx.x;
#pragma unroll
    for (int i = 0; i < 4; ++i) {
        int flat = i * 256 + t;
        int k = flat >> 4, c4 = (flat & 15) * 4;
        float4 v = *(const float4*)(src + (size_t)k * DM + c4);
        lt[k][c4] = v.x; lt[k][c4+1] = v.y; lt[k][c4+2] = v.z; lt[k][c4+3] = v.w;
    }
    __syncthreads();
    unsigned short* dst = WT + ((size_t)e * 1024 + nt * 64) * 2048 + kt * 64;
#pragma unroll
    for (int i = 0; i < 4; ++i) {
        int flat = i * 256 + t;
        int n = flat >> 4, kc = (flat & 15) * 4;
        unsigned int lo = (unsigned int)bf16_rne(lt[kc][n])   | ((unsigned int)bf16_rne(lt[kc+1][n]) << 16);
        unsigned int hi = (unsigned int)bf16_rne(lt[kc+2][n]) | ((unsigned int)bf16_rne(lt[kc+3][n]) << 16);
        *(uint2*)(dst + (size_t)n * 2048 + kc) = make_uint2(lo, hi);
    }
}

// ---------------- GEMM1: 128 rows x 64 hh-cols, 4 waves, 32KB, 4/CU ----------------
__global__ __launch_bounds__(256, 4) void k_gemm1(const unsigned short* __restrict__ xbf,
                                                  const unsigned short* __restrict__ W1T,
                                                  const float* __restrict__ b1,
                                                  const int* __restrict__ pair_tok,
                                                  const int* __restrict__ cnt_pad,
                                                  const int* __restrict__ off_pad,
                                                  unsigned short* __restrict__ hh, int h) {
    int id = blockIdx.x;
    int lid = (id & 7) * 512 + (id >> 3);
    int c0t = lid & 15, yt = (lid >> 4) & 31, e = lid >> 9;
    if (yt * 128 >= cnt_pad[e]) return;
    int row0 = off_pad[e] + yt * 128;
    int c0 = c0t * 64;
    const unsigned short* WTe = W1T + (size_t)e * 2048 * 1024;

    __shared__ unsigned short lA[128 * 64];
    __shared__ unsigned short lB[128 * 64];

    int t = threadIdx.x, w = t >> 6, l = t & 63;
    int wm = w >> 1, wn = w & 1;

    const unsigned short* asrc[4];
    const unsigned short* bsrc[4];
    unsigned short* adst[4];
    unsigned short* bdst[4];
    int c8 = ((l & 7) ^ (l >> 3)) * 8;
#pragma unroll
    for (int q = 0; q < 4; ++q) {
        int r = w * 32 + q * 8 + (l >> 3);
        int tok = pair_tok[row0 + r];
        asrc[q] = xbf + (size_t)tok * DM + c8;
        adst[q] = lA + (w * 32 + q * 8) * 64;
        int bn = (r < 64) ? (c0 + r) : (1024 + c0 + (r - 64));
        bsrc[q] = WTe + (size_t)bn * 1024 + c8;
        bdst[q] = lB + (w * 32 + q * 8) * 64;
    }

    f32x4 aca[4][2], acg[4][2];
#pragma unroll
    for (int m = 0; m < 4; ++m)
#pragma unroll
        for (int fn = 0; fn < 2; ++fn) { aca[m][fn] = (f32x4){0,0,0,0}; acg[m][fn] = (f32x4){0,0,0,0}; }

#pragma unroll
    for (int q = 0; q < 4; ++q) { gload16(asrc[q], adst[q]); gload16(bsrc[q], bdst[q]); }

    int lr = l & 15, kg = l >> 4;
    for (int kt = 0; kt < 16; ++kt) {
        __syncthreads();
#pragma unroll
        for (int ks = 0; ks < 2; ++ks) {
            int kc = ks * 64 + kg * 16;
            bf16x8 af[4];
#pragma unroll
            for (int m = 0; m < 4; ++m) {
                int row = wm * 64 + m * 16 + lr;
                af[m] = *(const bf16x8*)((const char*)lA + row * 128 + (kc ^ ((row & 7) << 4)));
            }
#pragma unroll
            for (int fn = 0; fn < 2; ++fn) {
                int na = wn * 32 + fn * 16 + lr;
                bf16x8 ba = *(const bf16x8*)((const char*)lB + na * 128 + (kc ^ ((na & 7) << 4)));
                bf16x8 bg = *(const bf16x8*)((const char*)lB + (na + 64) * 128 + (kc ^ ((na & 7) << 4)));
#pragma unroll
                for (int m = 0; m < 4; ++m) {
                    aca[m][fn] = MFMA16(af[m], ba, aca[m][fn]);
                    acg[m][fn] = MFMA16(af[m], bg, acg[m][fn]);
                }
            }
        }
        __syncthreads();
        if (kt < 15) {
#pragma unroll
            for (int q = 0; q < 4; ++q) {
                gload16(asrc[q] + (kt + 1) * 64, adst[q]);
                gload16(bsrc[q] + (kt + 1) * 64, bdst[q]);
            }
        }
    }
#pragma unroll
    for (int m = 0; m < 4; ++m)
#pragma unroll
        for (int fn = 0; fn < 2; ++fn) {
            int colh = h * 1024 + c0 + wn * 32 + fn * 16 + lr;
            float ba1 = b1[e * F2 + colh], bg1 = b1[e * F2 + FF + colh];
#pragma unroll
            for (int j = 0; j < 4; ++j) {
                int row = wm * 64 + m * 16 + kg * 4 + j;
                float a = aca[m][fn][j] + ba1;
                float g = acg[m][fn][j] + bg1;
                float sg = a / (1.f + __expf(-a)) * g;
                hh[(size_t)(row0 + row) * FF + colh] = bf16_rne(sg);
            }
        }
}

// ---------------- GEMM2: 128 rows x 64 d-cols, 4 waves, 24KB, 4/CU, eo stores ----------------
__global__ __launch_bounds__(256, 4) void k_gemm2(const unsigned short* __restrict__ hh,
                                                  const unsigned short* __restrict__ W2T,
                                                  const float* __restrict__ b2,
                                                  const int* __restrict__ pair_tok,
                                                  const float* __restrict__ pair_w,
                                                  const int* __restrict__ cnt_pad,
                                                  const int* __restrict__ off_pad,
                                                  float* __restrict__ eo_or_out, int mode) {
    int id = blockIdx.x;
    int lid = (id & 7) * 512 + (id >> 3);
    int d0t = lid & 15, yt = (lid >> 4) & 31, e = lid >> 9;
    if (yt * 128 >= cnt_pad[e]) return;
    int row0 = off_pad[e] + yt * 128;
    int d0 = d0t * 64;
    const unsigned short* WTe = W2T + (size_t)e * 1024 * 2048;

    __shared__ unsigned short lA[128 * 64];
    __shared__ unsigned short lB[64 * 64];

    int t = threadIdx.x, w = t >> 6, l = t & 63;
    int wm = w >> 1, wn = w & 1;

    const unsigned short* asrc[4];
    const unsigned short* bsrc[2];
    unsigned short* adst[4];
    unsigned short* bdst[2];
    int c8 = ((l & 7) ^ (l >> 3)) * 8;
#pragma unroll
    for (int q = 0; q < 4; ++q) {
        int r = w * 32 + q * 8 + (l >> 3);
        asrc[q] = hh + (size_t)(row0 + r) * FF + c8;
        adst[q] = lA + (w * 32 + q * 8) * 64;
    }
#pragma unroll
    for (int q = 0; q < 2; ++q) {
        int r = w * 16 + q * 8 + (l >> 3);
        bsrc[q] = WTe + (size_t)(d0 + r) * 2048 + c8;
        bdst[q] = lB + (w * 16 + q * 8) * 64;
    }

    f32x4 ac[4][2];
#pragma unroll
    for (int m = 0; m < 4; ++m)
#pragma unroll
        for (int fn = 0; fn < 2; ++fn) ac[m][fn] = (f32x4){0,0,0,0};

#pragma unroll
    for (int q = 0; q < 4; ++q) gload16(asrc[q], adst[q]);
#pragma unroll
    for (int q = 0; q < 2; ++q) gload16(bsrc[q], bdst[q]);

    int lr = l & 15, kg = l >> 4;
    for (int kt = 0; kt < 32; ++kt) {
        __syncthreads();
#pragma unroll
        for (int ks = 0; ks < 2; ++ks) {
            int kc = ks * 64 + kg * 16;
            bf16x8 af[4];
#pragma unroll
            for (int m = 0; m < 4; ++m) {
                int row = wm * 64 + m * 16 + lr;
                af[m] = *(const bf16x8*)((const char*)lA + row * 128 + (kc ^ ((row & 7) << 4)));
            }
#pragma unroll
            for (int fn = 0; fn < 2; ++fn) {
                int n = wn * 32 + fn * 16 + lr;
                bf16x8 bb = *(const bf16x8*)((const char*)lB + n * 128 + (kc ^ ((n & 7) << 4)));
#pragma unroll
                for (int m = 0; m < 4; ++m) ac[m][fn] = MFMA16(af[m], bb, ac[m][fn]);
            }
        }
        __syncthreads();
        if (kt < 31) {
#pragma unroll
            for (int q = 0; q < 4; ++q) gload16(asrc[q] + (kt + 1) * 64, adst[q]);
#pragma unroll
            for (int q = 0; q < 2; ++q) gload16(bsrc[q] + (kt + 1) * 64, bdst[q]);
        }
    }

    if (mode == 0) {
#pragma unroll
        for (int m = 0; m < 4; ++m)
#pragma unroll
            for (int fn = 0; fn < 2; ++fn) {
                int col = d0 + wn * 32 + fn * 16 + lr;
#pragma unroll
                for (int j = 0; j < 4; ++j) {
                    int row = wm * 64 + m * 16 + kg * 4 + j;
                    int pr = row0 + row;
                    eo_or_out[(size_t)pr * DM + col] = pair_w[pr] * ac[m][fn][j];
                }
            }
    } else {
#pragma unroll
        for (int m = 0; m < 4; ++m)
#pragma unroll
            for (int fn = 0; fn < 2; ++fn) {
                int col = d0 + wn * 32 + fn * 16 + lr;
                float b2v = b2[e * DM + col];
#pragma unroll
                for (int j = 0; j < 4; ++j) {
                    int row = wm * 64 + m * 16 + kg * 4 + j;
                    int pr = row0 + row;
                    atomicAdd(eo_or_out + (size_t)pair_tok[pr] * DM + col,
                              pair_w[pr] * (ac[m][fn][j] + b2v));
                }
            }
    }
}

// ---------------- combine: out[t] = eo[s0]+eo[s1] + w0*b2[e0] + w1*b2[e1] ----------------
__global__ __launch_bounds__(256) void k_comb(const float* __restrict__ eo,
                                              const int* __restrict__ slot_of,
                                              const int* __restrict__ te,
                                              const float* __restrict__ tw,
                                              const float* __restrict__ b2,
                                              float* __restrict__ out) {
    int t = blockIdx.x;
    int d = threadIdx.x * 4;
    int s0 = slot_of[2*t], s1 = slot_of[2*t+1];
    int e0 = te[2*t], e1 = te[2*t+1];
    float w0 = tw[2*t], w1 = tw[2*t+1];
    float4 a = *(const float4*)(eo + (size_t)s0 * DM + d);
    float4 b = *(const float4*)(eo + (size_t)s1 * DM + d);
    float4 p = *(const float4*)(b2 + (size_t)e0 * DM + d);
    float4 q = *(const float4*)(b2 + (size_t)e1 * DM + d);
    float4 r;
    r.x = a.x + b.x + w0 * p.x + w1 * q.x;
    r.y = a.y + b.y + w0 * p.y + w1 * q.y;
    r.z = a.z + b.z + w0 * p.z + w1 * q.z;
    r.w = a.w + b.w + w0 * p.w + w1 * q.w;
    *(float4*)(out + (size_t)t * DM + d) = r;
}

// ---------------- host ----------------
extern "C" void kernel_launch(void* const* d_in, const int* in_sizes, int n_in,
                              void* d_out, int out_size, void* d_ws, size_t ws_size,
                              hipStream_t stream) {
    const float* x  = (const float*)d_in[0];
    const float* Wg = (const float*)d_in[1];
    const float* W1 = (const float*)d_in[2];
    const float* b1 = (const float*)d_in[3];
    const float* W2 = (const float*)d_in[4];
    const float* b2 = (const float*)d_in[5];
    float* out = (float*)d_out;

    char* ws = (char*)d_ws;
    unsigned short* xbf = (unsigned short*)ws;                        // 8.39 MB
    unsigned short* hh  = (unsigned short*)(ws + 8388608);            // 41.94 MB
    unsigned short* WT  = (unsigned short*)(ws + 50331648);           // 33.55 MB
    float* eo           = (float*)(ws + 83886080);                    // 37.75 MB (mode 0 only)
    const size_t EO_END = 83886080ull + 37748736ull;                  // 121.6 MB
    const size_t MISC_NEED = 262144;
    int mode = (ws_size >= EO_END + MISC_NEED) ? 0 : 1;
    size_t mb = (mode == 0) ? EO_END : 83886080ull;
    int*   pair_tok = (int*)(ws + mb);
    float* pair_w   = (float*)(ws + mb + 40960);
    int*   slot_of  = (int*)(ws + mb + 81920);
    int*   te       = (int*)(ws + mb + 114688);
    float* tw       = (float*)(ws + mb + 147456);
    int*   cnt_pad  = (int*)(ws + mb + 180224);
    int*   off_pad  = (int*)(ws + mb + 180352);

    if (mode == 1)
        hipMemsetAsync(d_out, 0, (size_t)out_size * sizeof(float), stream);

    k_gate<<<NTOK / 4, 256, 0, stream>>>(x, Wg, xbf, te, tw);
    k_route<<<1, 256, 0, stream>>>(te, tw, pair_tok, pair_w, slot_of, cnt_pad, off_pad);

    for (int h = 0; h < 2; ++h) {
        k_cvt1<<<dim3(16, 32, 8), 256, 0, stream>>>(W1, WT, h);
        k_gemm1<<<4096, 256, 0, stream>>>(xbf, WT, b1, pair_tok, cnt_pad, off_pad, hh, h);
    }
    k_cvt2<<<dim3(32, 16, 8), 256, 0, stream>>>(W2, WT);
    k_gemm2<<<4096, 256, 0, stream>>>(hh, WT, b2, pair_tok, pair_w, cnt_pad, off_pad,
                                      (mode == 0) ? eo : out, mode);
    if (mode == 0)
        k_comb<<<NTOK, 256, 0, stream>>>(eo, slot_of, te, tw, b2, out);
}